// Round 2
// baseline (521.564 us; speedup 1.0000x reference)
//
#include <hip/hip_runtime.h>

// DeformConv2d fused kernel, fp32.
// B=8, C=64, H=W=64, Cout=64, GROUPS=4, K=9, stride 1, pad 1, dil 1.
//
// One 8x8 output tile per block, 256 threads = 4 waves.
// wave index jw = softmax group = output-channel group (c = jw*16 + cg).
// Offset-conv weights are wave-uniform (readfirstlane) -> scalar s_load path.
// Patch (64ch x 10x10 halo) in LDS fp32; main-conv weights transposed in LDS
// bf16 (keeps static LDS at 53.5 KB); softmax-logit exchange across waves via LDS.

#define PCS 101                       // patch channel stride (10*10 + 1 pad)
#define LDS_PATCH_SZ (64 * PCS)       // 6464 floats
#define LDS_LOG_SZ   (4 * 64 * 9)     // 2304 floats

__device__ __forceinline__ unsigned short f32_to_bf16_rne(float f) {
    unsigned u = __float_as_uint(f);
    unsigned r = u + 0x7FFFu + ((u >> 16) & 1u);   // round-to-nearest-even
    return (unsigned short)(r >> 16);
}

__global__ __launch_bounds__(256, 2)
void deform_fused(const float* __restrict__ inps,
                  const float* __restrict__ weight,
                  const float* __restrict__ bias,
                  const float* __restrict__ woff,
                  const float* __restrict__ boff,
                  float* __restrict__ out)
{
    __shared__ float  lds_f[LDS_PATCH_SZ + LDS_LOG_SZ];
    __shared__ unsigned short wmT[144 * 64];   // bf16 main weights, [r][o]

    float* patch = lds_f;                       // [ch][iy][ix] stride PCS
    float* lgx   = lds_f + LDS_PATCH_SZ;        // [j][pix][k]

    const int tid  = threadIdx.x;
    const int b    = blockIdx.x >> 6;
    const int tyle = blockIdx.x & 63;
    const int ty0  = (tyle >> 3) << 3;
    const int tx0  = (tyle & 7) << 3;

    const int lane = tid & 63;
    const int jw   = __builtin_amdgcn_readfirstlane(tid >> 6);  // wave-uniform group
    const int ty = lane >> 3, tx = lane & 7;
    const int oy = ty0 + ty, ox = tx0 + tx;

    const float* inb = inps + (size_t)b * (64 * 64 * 64);

    // ---- stage patch: 64 ch x 10x10 halo (zero-padded) ----
    for (int e = tid; e < 64 * 100; e += 256) {
        int ch = e / 100, rem = e - ch * 100;
        int iy = rem / 10, ix = rem - iy * 10;
        int gy = ty0 + iy - 1, gx = tx0 + ix - 1;
        float v = 0.f;
        if ((unsigned)gy < 64u && (unsigned)gx < 64u)
            v = inb[(ch * 64 + gy) * 64 + gx];
        patch[ch * PCS + iy * 10 + ix] = v;
    }
    // ---- stage main conv weights transposed, bf16: wmT[r*64+o] = w[o*144+r] ----
    for (int e = tid; e < 9216; e += 256) {
        int o = e / 144, r = e - o * 144;
        wmT[r * 64 + o] = f32_to_bf16_rne(weight[e]);
    }
    __syncthreads();

    float accO[16];
#pragma unroll
    for (int i = 0; i < 16; ++i) accO[i] = 0.f;

    for (int cg = 0; cg < 16; ++cg) {
        float acc[3][9];
#pragma unroll
        for (int c3 = 0; c3 < 3; ++c3)
#pragma unroll
            for (int k = 0; k < 9; ++k) acc[c3][k] = 0.f;

        // ---- offset conv: 3 comps x 9 k-channels, each a 144-dot ----
#pragma unroll
        for (int comp = 0; comp < 3; ++comp) {
            const int och0 = comp * 576 + (jw * 16 + cg) * 9;  // uniform
            const int g    = och0 / 432;                        // input group, uniform
            const float* wb = woff + (size_t)och0 * 144;        // 9x144 contiguous block
            const int pb0 = (g * 16) * PCS + ty * 10 + tx;
            for (int ci = 0; ci < 16; ++ci) {
                float pv[9];
                const int pbase = pb0 + ci * PCS;
#pragma unroll
                for (int t = 0; t < 9; ++t)
                    pv[t] = patch[pbase + (t / 3) * 10 + (t % 3)];
#pragma unroll
                for (int k = 0; k < 9; ++k) {
                    const float* wr = wb + k * 144 + ci * 9;    // uniform -> s_load
#pragma unroll
                    for (int t = 0; t < 9; ++t)
                        acc[comp][k] = fmaf(pv[t], wr[t], acc[comp][k]);
                }
            }
#pragma unroll
            for (int k = 0; k < 9; ++k) acc[comp][k] += boff[och0 + k];
        }

        // ---- exchange mask logits across the 4 waves ----
        __syncthreads();   // protect previous iteration's lgx readers
#pragma unroll
        for (int k = 0; k < 9; ++k)
            lgx[(jw * 64 + lane) * 9 + k] = acc[2][k];
        __syncthreads();

        const int c = jw * 16 + cg;
        const float* inc = inb + c * 4096;

#pragma unroll
        for (int k = 0; k < 9; ++k) {
            float l0 = lgx[(0 * 64 + lane) * 9 + k];
            float l1 = lgx[(1 * 64 + lane) * 9 + k];
            float l2 = lgx[(2 * 64 + lane) * 9 + k];
            float l3 = lgx[(3 * 64 + lane) * 9 + k];
            float m = fmaxf(fmaxf(l0, l1), fmaxf(l2, l3));
            float s = expf(l0 - m) + expf(l1 - m) + expf(l2 - m) + expf(l3 - m);
            float msk = expf(acc[2][k] - m) / s;

            // sample position in padded coords
            float py = (float)(oy + (k / 3)) + acc[0][k];
            float px = (float)(ox + (k % 3)) + acc[1][k];
            float y0f = floorf(py), x0f = floorf(px);
            float wy = py - y0f, wx = px - x0f;
            int iy0 = (int)y0f - 1, ix0 = (int)x0f - 1;  // raw-input coords
            float w00 = (1.f - wy) * (1.f - wx), w01 = (1.f - wy) * wx;
            float w10 = wy * (1.f - wx),         w11 = wy * wx;
            float v = 0.f;
            if ((unsigned)iy0 < 64u) {
                if ((unsigned)ix0 < 64u)       v += w00 * inc[iy0 * 64 + ix0];
                if ((unsigned)(ix0 + 1) < 64u) v += w01 * inc[iy0 * 64 + ix0 + 1];
            }
            if ((unsigned)(iy0 + 1) < 64u) {
                if ((unsigned)ix0 < 64u)       v += w10 * inc[(iy0 + 1) * 64 + ix0];
                if ((unsigned)(ix0 + 1) < 64u) v += w11 * inc[(iy0 + 1) * 64 + ix0 + 1];
            }
            float sv = v * msk;

            const unsigned short* wrow = &wmT[(cg * 9 + k) * 64 + jw * 16];
#pragma unroll
            for (int oo = 0; oo < 16; ++oo) {
                float wv = __uint_as_float((unsigned)wrow[oo] << 16);
                accO[oo] = fmaf(sv, wv, accO[oo]);
            }
        }
    }

    // ---- store ----
    float* outp = out + ((size_t)b * 64 + jw * 16) * 4096 + oy * 64 + ox;
#pragma unroll
    for (int oo = 0; oo < 16; ++oo)
        outp[oo * 4096] = accO[oo] + bias[jw * 16 + oo];
}

extern "C" void kernel_launch(void* const* d_in, const int* in_sizes, int n_in,
                              void* d_out, int out_size, void* d_ws, size_t ws_size,
                              hipStream_t stream) {
    const float* inps   = (const float*)d_in[0];
    const float* weight = (const float*)d_in[1];
    const float* bias   = (const float*)d_in[2];
    const float* woff   = (const float*)d_in[3];
    const float* boff   = (const float*)d_in[4];
    float* outp = (float*)d_out;
    deform_fused<<<dim3(512), dim3(256), 0, stream>>>(inps, weight, bias, woff, boff, outp);
}

// Round 3
// 263.695 us; speedup vs baseline: 1.9779x; 1.9779x over previous
//
#include <hip/hip_runtime.h>

// DeformConv2d fused, MFMA version.
// B=8, C=64, H=W=64, Cout=64, GROUPS=4, K=9.
// Per block: 32 px (8 wide x 4 tall), 256 thr = 4 waves; wave = softmax group jw.
// GEMM formulation (M=px, N=och, K=576 group-window-masked):
//   offset conv: D[px][och] = imc[px][kk] * woff[och][kk-window]  (bf16 MFMA)
//   main   conv: D[px][o]   = S[px][kk2]  * wmain[o][kk2-window]
// imc/S: bf16 [32][584] in LDS (pad 584 -> conflict-free ds_read_b128 frags).
// Softmax logits for the 4 groups share lane slot (och stride 144 == 0 mod 16);
// cross-wave exchange via small LGX buffer. Bilinear sampling reads global (L1/L2).

typedef __attribute__((ext_vector_type(8))) short short8;
typedef __attribute__((ext_vector_type(4))) float f32x4;

#define IMC_OFF   0
#define S_OFF     37376
#define LGX_OFF   74752
#define LDS_BYTES 78848

__device__ __forceinline__ unsigned cvtpk2(float lo, float hi) {
    unsigned r;
    asm("v_cvt_pk_bf16_f32 %0, %1, %2" : "=v"(r) : "v"(lo), "v"(hi));
    return r;
}
__device__ __forceinline__ unsigned short bf16rne(float f) {
    unsigned u = __float_as_uint(f);
    u += 0x7FFFu + ((u >> 16) & 1u);
    return (unsigned short)(u >> 16);
}
__device__ __forceinline__ float bf16dec(unsigned short h) {
    return __uint_as_float((unsigned)h << 16);
}

extern __shared__ char smem[];

__global__ __launch_bounds__(256, 2)
void deform_v2(const float* __restrict__ inps,
               const float* __restrict__ wmain,
               const float* __restrict__ bmain,
               const float* __restrict__ woff,
               const float* __restrict__ boff,
               float* __restrict__ out)
{
    unsigned short* IMC  = (unsigned short*)(smem + IMC_OFF);   // [32][584] bf16
    unsigned short* SBUF = (unsigned short*)(smem + S_OFF);     // [32][584] bf16
    unsigned short* LGX  = (unsigned short*)(smem + LGX_OFF);   // [4][32][16] bf16
    float* PATCH = (float*)(smem + S_OFF);                      // alias S during build: [64][61]
    float* OTB   = (float*)(smem + IMC_OFF);                    // alias imc at end: [64][33]

    const int tid  = threadIdx.x;
    const int lane = tid & 63;
    const int jw   = __builtin_amdgcn_readfirstlane(tid >> 6);  // wave = softmax group
    const int slot = lane & 15;                                 // N-col slot
    const int q    = lane >> 4;                                 // k-chunk / D-row group

    const int b    = blockIdx.x >> 7;        // 1024 blocks = 8 b x 128 tiles
    const int tile = blockIdx.x & 127;
    const int ty0  = (tile >> 3) << 2;       // 16 y-tiles of 4
    const int tx0  = (tile & 7) << 3;        // 8 x-tiles of 8

    const float* inb = inps + (size_t)b * 262144;

    // ---- phase 1: patch fp32, 64ch x 6y x 10x halo (zero OOB) ----
    for (int e = tid; e < 64 * 60; e += 256) {
        int ch = e / 60, rem = e - ch * 60;
        int iy = rem / 10, ix = rem - iy * 10;
        int gy = ty0 + iy - 1, gx = tx0 + ix - 1;
        float v = 0.f;
        if ((unsigned)gy < 64u && (unsigned)gx < 64u)
            v = inb[(ch * 64 + gy) * 64 + gx];
        PATCH[ch * 61 + rem] = v;
    }
    __syncthreads();

    // ---- phase 2: im2col bf16  IMC[px][kk], kk = c*9 + ky*3 + kx ----
    {
        const int px  = tid >> 3;     // 0..31
        const int sub = tid & 7;      // 8 threads per px, 72 kk each
        const int pyr = px >> 3, pxx = px & 7;
        unsigned short* dst = IMC + px * 584;
        for (int i = 0; i < 36; ++i) {
            int kk = sub * 72 + 2 * i;
            float v0, v1;
            { int c = kk / 9, r9 = kk - c * 9, ky = r9 / 3, kx = r9 - ky * 3;
              v0 = PATCH[c * 61 + (pyr + ky) * 10 + (pxx + kx)]; }
            { int k1 = kk + 1; int c = k1 / 9, r9 = k1 - c * 9, ky = r9 / 3, kx = r9 - ky * 3;
              v1 = PATCH[c * 61 + (pyr + ky) * 10 + (pxx + kx)]; }
            *(unsigned*)(dst + kk) = cvtpk2(v0, v1);
        }
    }
    __syncthreads();

    // ---- phase 3: ntg loop: offset GEMM -> softmax -> bilinear -> S ----
    for (int ntg = 0; ntg < 9; ++ntg) {
        f32x4 aD[2] = {{0.f,0.f,0.f,0.f},{0.f,0.f,0.f,0.f}};
        f32x4 aX[2] = {{0.f,0.f,0.f,0.f},{0.f,0.f,0.f,0.f}};
        f32x4 aM[2] = {{0.f,0.f,0.f,0.f},{0.f,0.f,0.f,0.f}};

        auto gemm3 = [&](f32x4* acc, int comp) {
            const int ochb = comp * 576 + jw * 144 + ntg * 16;  // tile base och
            const int g    = ochb / 432;                        // input group (uniform/tile)
            const int ktf  = (9 * g) >> 1;                      // first K-tile of window
            const int ch0  = g * 18;                            // first valid 8-chunk
            const int och  = ochb + slot;
            #pragma unroll
            for (int kt = 0; kt < 5; ++kt) {
                const int ktg   = ktf + kt;
                const int chunk = ktg * 4 + q;
                short8 bfr;
                if ((unsigned)(chunk - ch0) < 18u) {
                    const float4* wp = (const float4*)(woff + (size_t)och * 144 + (chunk - ch0) * 8);
                    float4 w0 = wp[0], w1 = wp[1];
                    union { unsigned u[4]; short8 s; } cv;
                    cv.u[0] = cvtpk2(w0.x, w0.y); cv.u[1] = cvtpk2(w0.z, w0.w);
                    cv.u[2] = cvtpk2(w1.x, w1.y); cv.u[3] = cvtpk2(w1.z, w1.w);
                    bfr = cv.s;
                } else {
                    bfr = short8{0,0,0,0,0,0,0,0};
                }
                #pragma unroll
                for (int mt = 0; mt < 2; ++mt) {
                    const short8* ap = (const short8*)(smem + IMC_OFF +
                                        (mt * 16 + slot) * 1168 + ktg * 64 + q * 16);
                    acc[mt] = __builtin_amdgcn_mfma_f32_16x16x32_bf16(*ap, bfr, acc[mt], 0, 0, 0);
                }
            }
            const float bo = boff[ochb + slot];
            #pragma unroll
            for (int mt = 0; mt < 2; ++mt) {
                acc[mt][0] += bo; acc[mt][1] += bo; acc[mt][2] += bo; acc[mt][3] += bo;
            }
        };
        gemm3(aD, 0); gemm3(aX, 1); gemm3(aM, 2);

        // exchange mask logits across waves
        #pragma unroll
        for (int mt = 0; mt < 2; ++mt)
        #pragma unroll
        for (int r = 0; r < 4; ++r) {
            int pxr = mt * 16 + q * 4 + r;
            LGX[(jw * 32 + pxr) * 16 + slot] = bf16rne(aM[mt][r]);
        }
        __syncthreads();

        const int rr  = ntg * 16 + slot;         // cg*9 + k
        const int cg  = rr / 9;
        const int kk9 = rr - cg * 9;
        const int kyk = kk9 / 3, kxk = kk9 - kyk * 3;
        const int c   = jw * 16 + cg;
        const float* inc = inb + c * 4096;

        #pragma unroll
        for (int mt = 0; mt < 2; ++mt)
        #pragma unroll
        for (int r = 0; r < 4; ++r) {
            const int pxr = mt * 16 + q * 4 + r;
            const int pyr = pxr >> 3, pxx = pxr & 7;
            float own = aM[mt][r];
            float l0 = (jw == 0) ? own : bf16dec(LGX[(0 * 32 + pxr) * 16 + slot]);
            float l1 = (jw == 1) ? own : bf16dec(LGX[(1 * 32 + pxr) * 16 + slot]);
            float l2 = (jw == 2) ? own : bf16dec(LGX[(2 * 32 + pxr) * 16 + slot]);
            float l3 = (jw == 3) ? own : bf16dec(LGX[(3 * 32 + pxr) * 16 + slot]);
            float m4 = fmaxf(fmaxf(l0, l1), fmaxf(l2, l3));
            float s4 = __expf(l0 - m4) + __expf(l1 - m4) + __expf(l2 - m4) + __expf(l3 - m4);
            float msk = __expf(own - m4) / s4;

            float pyf = (float)(ty0 + pyr + kyk - 1) + aD[mt][r];   // raw coords
            float pxf = (float)(tx0 + pxx + kxk - 1) + aX[mt][r];
            float y0f = floorf(pyf), x0f = floorf(pxf);
            float wy = pyf - y0f, wx = pxf - x0f;
            int iy0 = (int)y0f, ix0 = (int)x0f;
            float w00 = (1.f - wy) * (1.f - wx), w01 = (1.f - wy) * wx;
            float w10 = wy * (1.f - wx),         w11 = wy * wx;
            float v = 0.f;
            if ((unsigned)iy0 < 64u) {
                if ((unsigned)ix0 < 64u)       v += w00 * inc[iy0 * 64 + ix0];
                if ((unsigned)(ix0 + 1) < 64u) v += w01 * inc[iy0 * 64 + ix0 + 1];
            }
            if ((unsigned)(iy0 + 1) < 64u) {
                if ((unsigned)ix0 < 64u)       v += w10 * inc[(iy0 + 1) * 64 + ix0];
                if ((unsigned)(ix0 + 1) < 64u) v += w11 * inc[(iy0 + 1) * 64 + ix0 + 1];
            }
            SBUF[pxr * 584 + jw * 144 + rr] = bf16rne(v * msk);
        }
        __syncthreads();
    }

    // ---- phase 4: main conv GEMM (wave jw = o-group) ----
    {
        f32x4 aco[2] = {{0.f,0.f,0.f,0.f},{0.f,0.f,0.f,0.f}};
        const int ktf = (9 * jw) >> 1;
        const int ch0 = jw * 18;
        const int o   = jw * 16 + slot;
        #pragma unroll
        for (int kt = 0; kt < 5; ++kt) {
            const int ktg   = ktf + kt;
            const int chunk = ktg * 4 + q;
            short8 bfr;
            if ((unsigned)(chunk - ch0) < 18u) {
                const float4* wp = (const float4*)(wmain + (size_t)o * 144 + (chunk - ch0) * 8);
                float4 w0 = wp[0], w1 = wp[1];
                union { unsigned u[4]; short8 s; } cv;
                cv.u[0] = cvtpk2(w0.x, w0.y); cv.u[1] = cvtpk2(w0.z, w0.w);
                cv.u[2] = cvtpk2(w1.x, w1.y); cv.u[3] = cvtpk2(w1.z, w1.w);
                bfr = cv.s;
            } else {
                bfr = short8{0,0,0,0,0,0,0,0};
            }
            #pragma unroll
            for (int mt = 0; mt < 2; ++mt) {
                const short8* ap = (const short8*)(smem + S_OFF +
                                    (mt * 16 + slot) * 1168 + ktg * 64 + q * 16);
                aco[mt] = __builtin_amdgcn_mfma_f32_16x16x32_bf16(*ap, bfr, aco[mt], 0, 0, 0);
            }
        }
        const float bo = bmain[o];
        #pragma unroll
        for (int mt = 0; mt < 2; ++mt)
        #pragma unroll
        for (int r = 0; r < 4; ++r)
            OTB[o * 33 + mt * 16 + q * 4 + r] = aco[mt][r] + bo;
    }
    __syncthreads();

    // ---- coalesced store ----
    #pragma unroll
    for (int i = 0; i < 8; ++i) {
        int f  = i * 256 + tid;
        int oo = f >> 5, pp = f & 31;
        out[(size_t)(b * 64 + oo) * 4096 + (ty0 + (pp >> 3)) * 64 + (tx0 + (pp & 7))] =
            OTB[oo * 33 + pp];
    }
}

extern "C" void kernel_launch(void* const* d_in, const int* in_sizes, int n_in,
                              void* d_out, int out_size, void* d_ws, size_t ws_size,
                              hipStream_t stream) {
    const float* inps   = (const float*)d_in[0];
    const float* weight = (const float*)d_in[1];
    const float* bias   = (const float*)d_in[2];
    const float* woff   = (const float*)d_in[3];
    const float* boff   = (const float*)d_in[4];
    float* outp = (float*)d_out;
    hipFuncSetAttribute((const void*)deform_v2,
                        hipFuncAttributeMaxDynamicSharedMemorySize, LDS_BYTES);
    deform_v2<<<dim3(1024), dim3(256), LDS_BYTES, stream>>>(inps, weight, bias, woff, boff, outp);
}

// Round 4
// 222.229 us; speedup vs baseline: 2.3470x; 1.1866x over previous
//
#include <hip/hip_runtime.h>

typedef __attribute__((ext_vector_type(8))) short short8;
typedef __attribute__((ext_vector_type(4))) float f32x4;

__device__ __forceinline__ unsigned short bf16rne(float f) {
    unsigned u = __float_as_uint(f);
    u += 0x7FFFu + ((u >> 16) & 1u);
    return (unsigned short)(u >> 16);
}
__device__ __forceinline__ float bf16dec(unsigned short h) {
    return __uint_as_float((unsigned)h << 16);
}
__device__ __forceinline__ unsigned cvtpk2(float lo, float hi) {
    unsigned r;
    asm("v_cvt_pk_bf16_f32 %0, %1, %2" : "=v"(r) : "v"(lo), "v"(hi));
    return r;
}

extern __shared__ char smem[];

// ======================= v3: packed-weight fused kernel =======================
// LDS map (dynamic, 52736 B -> 3 blocks/CU):
//   IMC  [32 px][600] bf16   @0      (38400 B)  im2col, stride 75 short8
//   SX   [4 jw][32][40] bf16 @38400  (10240 B)  sampled-value exchange (per-wave)
//   LGX  [4 jw][32][16] bf16 @48640  ( 4096 B)  softmax logits (cross-wave)
//   PATCH alias @38400 (7680 B, phase 1-2 only); OTB alias @38400 (8448 B, epilogue)

#define IMC3_OFF   0
#define SX3_OFF    38400
#define LGX3_OFF   48640
#define LDS_V3     52736
#define PATCH3_OFF 38400
#define OTB3_OFF   38400

#define PWOFF_U32  138240   // 108 tiles * 5 kt * 64 lanes * 4 u32 (16x16x32 B-frags)
#define PWM_U32    5120     // 4 jw * 5 pairs * 64 lanes * 4 u32
#define WS_NEEDED  ((size_t)(PWOFF_U32 + PWM_U32) * 4)

__global__ __launch_bounds__(256)
void pack_weights(const float* __restrict__ wmain,
                  const float* __restrict__ woff,
                  unsigned* __restrict__ pw)
{
    int idx = blockIdx.x * 256 + threadIdx.x;
    if (idx < PWOFF_U32) {
        int j2   = idx & 3;
        int lane = (idx >> 2) & 63;
        int rest = idx >> 8;              // t*5 + kt
        int kt   = rest % 5;
        int t    = rest / 5;
        int comp = t / 36, r36 = t - comp * 36;
        int jw   = r36 / 9, ntg = r36 - jw * 9;
        int ochb = comp * 576 + jw * 144 + ntg * 16;
        int g    = ochb / 432;
        int ktf  = (9 * g) >> 1;
        int och  = ochb + (lane & 15);
        int ck   = (ktf + kt) * 32 + (lane >> 4) * 8 + j2 * 2 - g * 144;
        float v0 = 0.f, v1 = 0.f;
        if ((unsigned)ck < 144u)       v0 = woff[(size_t)och * 144 + ck];
        if ((unsigned)(ck + 1) < 144u) v1 = woff[(size_t)och * 144 + ck + 1];
        pw[idx] = (unsigned)bf16rne(v0) | ((unsigned)bf16rne(v1) << 16);
    } else if (idx < PWOFF_U32 + PWM_U32) {
        int m    = idx - PWOFF_U32;
        int j2   = m & 3;
        int lane = (m >> 2) & 63;
        int rest = m >> 8;                // jw*5 + pair
        int jw   = rest / 5, pair = rest - jw * 5;
        int och  = jw * 16 + (lane & 15);
        int w0   = pair * 32 + (lane >> 4) * 8 + j2 * 2;
        float v0 = (w0 < 144)     ? wmain[(size_t)och * 144 + w0]     : 0.f;
        float v1 = (w0 + 1 < 144) ? wmain[(size_t)och * 144 + w0 + 1] : 0.f;
        pw[idx] = (unsigned)bf16rne(v0) | ((unsigned)bf16rne(v1) << 16);
    }
}

__global__ __launch_bounds__(256, 3)
void deform_v3(const float* __restrict__ inps,
               const float* __restrict__ bmain,
               const float* __restrict__ boff,
               const unsigned short* __restrict__ pwoff,
               const unsigned short* __restrict__ pwm,
               float* __restrict__ out)
{
    unsigned short* IMC   = (unsigned short*)(smem + IMC3_OFF);
    unsigned short* SX    = (unsigned short*)(smem + SX3_OFF);
    unsigned short* LGX   = (unsigned short*)(smem + LGX3_OFF);
    unsigned short* PATCH = (unsigned short*)(smem + PATCH3_OFF);
    float*          OTB   = (float*)(smem + OTB3_OFF);

    const int tid  = threadIdx.x;
    const int lane = tid & 63;
    const int jw   = __builtin_amdgcn_readfirstlane(tid >> 6);
    const int slot = lane & 15;
    const int q    = lane >> 4;

    const int b    = blockIdx.x >> 7;
    const int tile = blockIdx.x & 127;
    const int ty0  = (tile >> 3) << 2;     // 16 y-tiles of 4
    const int tx0  = (tile & 7) << 3;      // 8 x-tiles of 8

    const float* inb = inps + (size_t)b * 262144;

    // ---- phase 1: PATCH bf16 [64 ch][6 y][10 x], zero OOB ----
    for (int e = tid; e < 3840; e += 256) {
        int ch = e / 60, rem = e - ch * 60;
        int iy = rem / 10, ix = rem - iy * 10;
        int gy = ty0 + iy - 1, gx = tx0 + ix - 1;
        float v = 0.f;
        if ((unsigned)gy < 64u && (unsigned)gx < 64u)
            v = inb[(ch * 64 + gy) * 64 + gx];
        PATCH[e] = bf16rne(v);
    }
    __syncthreads();

    // ---- phase 2: im2col IMC[px][kk], kk = c*9 + ky*3 + kx ----
    {
        const int px  = tid >> 3;          // 0..31
        const int sub = tid & 7;
        const int pyr = px >> 3, pxx = px & 7;
        unsigned* dst = (unsigned*)(IMC + px * 600);
        #pragma unroll 4
        for (int i = 0; i < 36; ++i) {
            int kk = i * 16 + sub * 2;
            int c0 = kk / 9,        r0 = kk - c0 * 9;
            int c1 = (kk + 1) / 9,  r1 = (kk + 1) - c1 * 9;
            unsigned short a  = PATCH[c0 * 60 + (pyr + r0 / 3) * 10 + pxx + r0 % 3];
            unsigned short bb = PATCH[c1 * 60 + (pyr + r1 / 3) * 10 + pxx + r1 % 3];
            dst[(unsigned)kk >> 1] = (unsigned)a | ((unsigned)bb << 16);
        }
    }
    __syncthreads();

    f32x4 aco[2] = {{0.f,0.f,0.f,0.f},{0.f,0.f,0.f,0.f}};

    auto pair_mfma = [&](int pair) {
        const short8 bfr = ((const short8*)pwm)[(jw * 5 + pair) * 64 + lane];
        #pragma unroll
        for (int mt = 0; mt < 2; ++mt) {
            const short8 a8 = *(const short8*)(SX + jw * 1280 + (mt * 16 + slot) * 40 + q * 8);
            aco[mt] = __builtin_amdgcn_mfma_f32_16x16x32_bf16(a8, bfr, aco[mt], 0, 0, 0);
        }
    };

    // ---- phase 3: ntg loop ----
    for (int ntg = 0; ntg < 9; ++ntg) {
        f32x4 aD[2] = {{0.f,0.f,0.f,0.f},{0.f,0.f,0.f,0.f}};
        f32x4 aX[2] = {{0.f,0.f,0.f,0.f},{0.f,0.f,0.f,0.f}};
        f32x4 aM[2] = {{0.f,0.f,0.f,0.f},{0.f,0.f,0.f,0.f}};

        auto gemm3 = [&](f32x4* acc, int comp) {
            const int ochb = comp * 576 + jw * 144 + ntg * 16;
            const int g    = ochb / 432;
            const int ktf  = (9 * g) >> 1;
            const int t    = comp * 36 + jw * 9 + ntg;
            const short8* wp  = (const short8*)pwoff + t * 320 + lane;   // + kt*64
            const short8* ap0 = (const short8*)(smem + IMC3_OFF);
            #pragma unroll
            for (int kt = 0; kt < 5; ++kt) {
                const short8 bfr = wp[kt * 64];
                const int ktg = ktf + kt;
                #pragma unroll
                for (int mt = 0; mt < 2; ++mt) {
                    const short8 af = ap0[(mt * 16 + slot) * 75 + ktg * 4 + q];
                    acc[mt] = __builtin_amdgcn_mfma_f32_16x16x32_bf16(af, bfr, acc[mt], 0, 0, 0);
                }
            }
            const float bo = boff[ochb + slot];
            #pragma unroll
            for (int mt = 0; mt < 2; ++mt) {
                acc[mt][0] += bo; acc[mt][1] += bo; acc[mt][2] += bo; acc[mt][3] += bo;
            }
        };
        gemm3(aD, 0); gemm3(aX, 1); gemm3(aM, 2);

        // logits -> LGX (cross-wave)
        #pragma unroll
        for (int mt = 0; mt < 2; ++mt)
        #pragma unroll
        for (int r = 0; r < 4; ++r)
            LGX[jw * 512 + (mt * 16 + q * 4 + r) * 16 + slot] = bf16rne(aM[mt][r]);
        __syncthreads();

        // sampling
        const int rr  = ntg * 16 + slot;
        const int cg  = rr / 9;
        const int kk9 = rr - cg * 9;
        const int kyk = kk9 / 3, kxk = kk9 - kyk * 3;
        const float* inc = inb + (jw * 16 + cg) * 4096;
        const int par = ntg & 1;

        #pragma unroll
        for (int mt = 0; mt < 2; ++mt)
        #pragma unroll
        for (int r = 0; r < 4; ++r) {
            const int pxr = mt * 16 + q * 4 + r;
            const int pyr = pxr >> 3, pxx = pxr & 7;
            const float own = aM[mt][r];
            float s4 = 0.f;
            #pragma unroll
            for (int j2 = 0; j2 < 4; ++j2)
                s4 += __expf(bf16dec(LGX[j2 * 512 + pxr * 16 + slot]) - own);
            const float msk = 1.0f / s4;

            float pyf = (float)(ty0 + pyr + kyk - 1) + aD[mt][r];
            float pxf = (float)(tx0 + pxx + kxk - 1) + aX[mt][r];
            float y0f = floorf(pyf), x0f = floorf(pxf);
            float wy = pyf - y0f, wx = pxf - x0f;
            int iy0 = (int)y0f, ix0 = (int)x0f;
            float w00 = (1.f - wy) * (1.f - wx), w01 = (1.f - wy) * wx;
            float w10 = wy * (1.f - wx),         w11 = wy * wx;
            float v = 0.f;
            if ((unsigned)iy0 < 64u) {
                if ((unsigned)ix0 < 64u)       v += w00 * inc[iy0 * 64 + ix0];
                if ((unsigned)(ix0 + 1) < 64u) v += w01 * inc[iy0 * 64 + ix0 + 1];
            }
            if ((unsigned)(iy0 + 1) < 64u) {
                if ((unsigned)ix0 < 64u)       v += w10 * inc[(iy0 + 1) * 64 + ix0];
                if ((unsigned)(ix0 + 1) < 64u) v += w11 * inc[(iy0 + 1) * 64 + ix0 + 1];
            }
            SX[jw * 1280 + pxr * 40 + par * 16 + slot] = bf16rne(v * msk);
        }

        // main-conv partial GEMM every completed pair (same-wave SX -> no barrier)
        if (ntg & 1)  { asm volatile("" ::: "memory"); pair_mfma(ntg >> 1); }
        if (ntg == 8) { asm volatile("" ::: "memory"); pair_mfma(4); }
        __syncthreads();
    }

    // ---- epilogue: transpose via OTB, coalesced store ----
    {
        const int o = jw * 16 + slot;
        const float bo = bmain[o];
        #pragma unroll
        for (int mt = 0; mt < 2; ++mt)
        #pragma unroll
        for (int r = 0; r < 4; ++r)
            OTB[o * 33 + mt * 16 + q * 4 + r] = aco[mt][r] + bo;
    }
    __syncthreads();
    #pragma unroll
    for (int i = 0; i < 8; ++i) {
        int f  = i * 256 + tid;
        int oo = f >> 5, pp = f & 31;
        out[(size_t)(b * 64 + oo) * 4096 + (ty0 + (pp >> 3)) * 64 + (tx0 + (pp & 7))] =
            OTB[oo * 33 + pp];
    }
}

// ======================= v2 fallback (proven, 263 us) =======================
#define V2IMC_OFF   0
#define V2S_OFF     37376
#define V2LGX_OFF   74752
#define V2LDS_BYTES 78848

__global__ __launch_bounds__(256, 2)
void deform_v2(const float* __restrict__ inps,
               const float* __restrict__ wmain,
               const float* __restrict__ bmain,
               const float* __restrict__ woff,
               const float* __restrict__ boff,
               float* __restrict__ out)
{
    unsigned short* IMC  = (unsigned short*)(smem + V2IMC_OFF);
    unsigned short* SBUF = (unsigned short*)(smem + V2S_OFF);
    unsigned short* LGX  = (unsigned short*)(smem + V2LGX_OFF);
    float* PATCH = (float*)(smem + V2S_OFF);
    float* OTB   = (float*)(smem + V2IMC_OFF);

    const int tid  = threadIdx.x;
    const int lane = tid & 63;
    const int jw   = __builtin_amdgcn_readfirstlane(tid >> 6);
    const int slot = lane & 15;
    const int q    = lane >> 4;

    const int b    = blockIdx.x >> 7;
    const int tile = blockIdx.x & 127;
    const int ty0  = (tile >> 3) << 2;
    const int tx0  = (tile & 7) << 3;

    const float* inb = inps + (size_t)b * 262144;

    for (int e = tid; e < 64 * 60; e += 256) {
        int ch = e / 60, rem = e - ch * 60;
        int iy = rem / 10, ix = rem - iy * 10;
        int gy = ty0 + iy - 1, gx = tx0 + ix - 1;
        float v = 0.f;
        if ((unsigned)gy < 64u && (unsigned)gx < 64u)
            v = inb[(ch * 64 + gy) * 64 + gx];
        PATCH[ch * 61 + rem] = v;
    }
    __syncthreads();
    {
        const int px  = tid >> 3;
        const int sub = tid & 7;
        const int pyr = px >> 3, pxx = px & 7;
        unsigned short* dst = IMC + px * 584;
        for (int i = 0; i < 36; ++i) {
            int kk = sub * 72 + 2 * i;
            float v0, v1;
            { int c = kk / 9, r9 = kk - c * 9, ky = r9 / 3, kx = r9 - ky * 3;
              v0 = PATCH[c * 61 + (pyr + ky) * 10 + (pxx + kx)]; }
            { int k1 = kk + 1; int c = k1 / 9, r9 = k1 - c * 9, ky = r9 / 3, kx = r9 - ky * 3;
              v1 = PATCH[c * 61 + (pyr + ky) * 10 + (pxx + kx)]; }
            *(unsigned*)(dst + kk) = cvtpk2(v0, v1);
        }
    }
    __syncthreads();

    for (int ntg = 0; ntg < 9; ++ntg) {
        f32x4 aD[2] = {{0.f,0.f,0.f,0.f},{0.f,0.f,0.f,0.f}};
        f32x4 aX[2] = {{0.f,0.f,0.f,0.f},{0.f,0.f,0.f,0.f}};
        f32x4 aM[2] = {{0.f,0.f,0.f,0.f},{0.f,0.f,0.f,0.f}};

        auto gemm3 = [&](f32x4* acc, int comp) {
            const int ochb = comp * 576 + jw * 144 + ntg * 16;
            const int g    = ochb / 432;
            const int ktf  = (9 * g) >> 1;
            const int ch0  = g * 18;
            const int och  = ochb + slot;
            #pragma unroll
            for (int kt = 0; kt < 5; ++kt) {
                const int ktg   = ktf + kt;
                const int chunk = ktg * 4 + q;
                short8 bfr;
                if ((unsigned)(chunk - ch0) < 18u) {
                    const float4* wp = (const float4*)(woff + (size_t)och * 144 + (chunk - ch0) * 8);
                    float4 w0 = wp[0], w1 = wp[1];
                    union { unsigned u[4]; short8 s; } cv;
                    cv.u[0] = cvtpk2(w0.x, w0.y); cv.u[1] = cvtpk2(w0.z, w0.w);
                    cv.u[2] = cvtpk2(w1.x, w1.y); cv.u[3] = cvtpk2(w1.z, w1.w);
                    bfr = cv.s;
                } else {
                    bfr = short8{0,0,0,0,0,0,0,0};
                }
                #pragma unroll
                for (int mt = 0; mt < 2; ++mt) {
                    const short8* ap = (const short8*)(smem + V2IMC_OFF +
                                        (mt * 16 + slot) * 1168 + ktg * 64 + q * 16);
                    acc[mt] = __builtin_amdgcn_mfma_f32_16x16x32_bf16(*ap, bfr, acc[mt], 0, 0, 0);
                }
            }
            const float bo = boff[ochb + slot];
            #pragma unroll
            for (int mt = 0; mt < 2; ++mt) {
                acc[mt][0] += bo; acc[mt][1] += bo; acc[mt][2] += bo; acc[mt][3] += bo;
            }
        };
        gemm3(aD, 0); gemm3(aX, 1); gemm3(aM, 2);

        #pragma unroll
        for (int mt = 0; mt < 2; ++mt)
        #pragma unroll
        for (int r = 0; r < 4; ++r) {
            int pxr = mt * 16 + q * 4 + r;
            LGX[(jw * 32 + pxr) * 16 + slot] = bf16rne(aM[mt][r]);
        }
        __syncthreads();

        const int rr  = ntg * 16 + slot;
        const int cg  = rr / 9;
        const int kk9 = rr - cg * 9;
        const int kyk = kk9 / 3, kxk = kk9 - kyk * 3;
        const float* inc = inb + (jw * 16 + cg) * 4096;

        #pragma unroll
        for (int mt = 0; mt < 2; ++mt)
        #pragma unroll
        for (int r = 0; r < 4; ++r) {
            const int pxr = mt * 16 + q * 4 + r;
            const int pyr = pxr >> 3, pxx = pxr & 7;
            float own = aM[mt][r];
            float l0 = (jw == 0) ? own : bf16dec(LGX[(0 * 32 + pxr) * 16 + slot]);
            float l1 = (jw == 1) ? own : bf16dec(LGX[(1 * 32 + pxr) * 16 + slot]);
            float l2 = (jw == 2) ? own : bf16dec(LGX[(2 * 32 + pxr) * 16 + slot]);
            float l3 = (jw == 3) ? own : bf16dec(LGX[(3 * 32 + pxr) * 16 + slot]);
            float m4 = fmaxf(fmaxf(l0, l1), fmaxf(l2, l3));
            float s4 = __expf(l0 - m4) + __expf(l1 - m4) + __expf(l2 - m4) + __expf(l3 - m4);
            float msk = __expf(own - m4) / s4;

            float pyf = (float)(ty0 + pyr + kyk - 1) + aD[mt][r];
            float pxf = (float)(tx0 + pxx + kxk - 1) + aX[mt][r];
            float y0f = floorf(pyf), x0f = floorf(pxf);
            float wy = pyf - y0f, wx = pxf - x0f;
            int iy0 = (int)y0f, ix0 = (int)x0f;
            float w00 = (1.f - wy) * (1.f - wx), w01 = (1.f - wy) * wx;
            float w10 = wy * (1.f - wx),         w11 = wy * wx;
            float v = 0.f;
            if ((unsigned)iy0 < 64u) {
                if ((unsigned)ix0 < 64u)       v += w00 * inc[iy0 * 64 + ix0];
                if ((unsigned)(ix0 + 1) < 64u) v += w01 * inc[iy0 * 64 + ix0 + 1];
            }
            if ((unsigned)(iy0 + 1) < 64u) {
                if ((unsigned)ix0 < 64u)       v += w10 * inc[(iy0 + 1) * 64 + ix0];
                if ((unsigned)(ix0 + 1) < 64u) v += w11 * inc[(iy0 + 1) * 64 + ix0 + 1];
            }
            SBUF[pxr * 584 + jw * 144 + rr] = bf16rne(v * msk);
        }
        __syncthreads();
    }

    {
        f32x4 aco2[2] = {{0.f,0.f,0.f,0.f},{0.f,0.f,0.f,0.f}};
        const int ktf = (9 * jw) >> 1;
        const int ch0 = jw * 18;
        const int o   = jw * 16 + slot;
        #pragma unroll
        for (int kt = 0; kt < 5; ++kt) {
            const int ktg   = ktf + kt;
            const int chunk = ktg * 4 + q;
            short8 bfr;
            if ((unsigned)(chunk - ch0) < 18u) {
                const float4* wp = (const float4*)(wmain + (size_t)o * 144 + (chunk - ch0) * 8);
                float4 w0 = wp[0], w1 = wp[1];
                union { unsigned u[4]; short8 s; } cv;
                cv.u[0] = cvtpk2(w0.x, w0.y); cv.u[1] = cvtpk2(w0.z, w0.w);
                cv.u[2] = cvtpk2(w1.x, w1.y); cv.u[3] = cvtpk2(w1.z, w1.w);
                bfr = cv.s;
            } else {
                bfr = short8{0,0,0,0,0,0,0,0};
            }
            #pragma unroll
            for (int mt = 0; mt < 2; ++mt) {
                const short8* ap = (const short8*)(smem + V2S_OFF +
                                    (mt * 16 + slot) * 1168 + ktg * 64 + q * 16);
                aco2[mt] = __builtin_amdgcn_mfma_f32_16x16x32_bf16(*ap, bfr, aco2[mt], 0, 0, 0);
            }
        }
        const float bo = bmain[o];
        __syncthreads();
        #pragma unroll
        for (int mt = 0; mt < 2; ++mt)
        #pragma unroll
        for (int r = 0; r < 4; ++r)
            OTB[o * 33 + mt * 16 + q * 4 + r] = aco2[mt][r] + bo;
    }
    __syncthreads();
    #pragma unroll
    for (int i = 0; i < 8; ++i) {
        int f  = i * 256 + tid;
        int oo = f >> 5, pp = f & 31;
        out[(size_t)(b * 64 + oo) * 4096 + (ty0 + (pp >> 3)) * 64 + (tx0 + (pp & 7))] =
            OTB[oo * 33 + pp];
    }
}

extern "C" void kernel_launch(void* const* d_in, const int* in_sizes, int n_in,
                              void* d_out, int out_size, void* d_ws, size_t ws_size,
                              hipStream_t stream) {
    const float* inps   = (const float*)d_in[0];
    const float* weight = (const float*)d_in[1];
    const float* bias   = (const float*)d_in[2];
    const float* woff   = (const float*)d_in[3];
    const float* boff   = (const float*)d_in[4];
    float* outp = (float*)d_out;

    if (ws_size >= WS_NEEDED) {
        unsigned* pw = (unsigned*)d_ws;
        pack_weights<<<dim3(560), dim3(256), 0, stream>>>(weight, woff, pw);
        hipFuncSetAttribute((const void*)deform_v3,
                            hipFuncAttributeMaxDynamicSharedMemorySize, LDS_V3);
        deform_v3<<<dim3(1024), dim3(256), LDS_V3, stream>>>(
            inps, bias, boff,
            (const unsigned short*)pw,
            (const unsigned short*)(pw + PWOFF_U32), outp);
    } else {
        hipFuncSetAttribute((const void*)deform_v2,
                            hipFuncAttributeMaxDynamicSharedMemorySize, V2LDS_BYTES);
        deform_v2<<<dim3(1024), dim3(256), V2LDS_BYTES, stream>>>(
            inps, weight, bias, woff, boff, outp);
    }
}

// Round 5
// 141.898 us; speedup vs baseline: 3.6756x; 1.5661x over previous
//
#include <hip/hip_runtime.h>

typedef __attribute__((ext_vector_type(8))) short short8;
typedef __attribute__((ext_vector_type(4))) float f32x4;

__device__ __forceinline__ unsigned short bf16rne(float f) {
    unsigned u = __float_as_uint(f);
    u += 0x7FFFu + ((u >> 16) & 1u);
    return (unsigned short)(u >> 16);
}
__device__ __forceinline__ float bf16dec(unsigned short h) {
    return __uint_as_float((unsigned)h << 16);
}
__device__ __forceinline__ unsigned cvtpk2(float lo, float hi) {
    unsigned r;
    asm("v_cvt_pk_bf16_f32 %0, %1, %2" : "=v"(r) : "v"(lo), "v"(hi));
    return r;
}

extern __shared__ char smem[];

// ======================= v4: LDS-patch bilinear sampling =======================
// LDS map (dynamic, 77312 B -> 2 blocks/CU):
//   IMC   [32 px][584] bf16  @0      (37376 B)  im2col A-matrix
//   PATCH [64 ch][12][16]    @37376  (25344 B)  bf16 halo-4 patch, stride 198 sh
//   SX    [4 jw][32][40]     @62720  (10240 B)  sampled-value A-frags (per-wave)
//   LGX   [32 px][17sl][4j]  @72960  ( 4352 B)  softmax logits, b64-readable
//   OTB alias @37376 (8448 B, epilogue only)

#define IMC4_OFF   0
#define PATCH4_OFF 37376
#define SX4_OFF    62720
#define LGX4_OFF   72960
#define LDS_V4     77312
#define OTB4_OFF   37376

#define PWOFF_U32  138240   // 108 tiles * 5 kt * 64 lanes * 4 u32 (16x16x32 B-frags)
#define PWM_U32    5120     // 4 jw * 5 pairs * 64 lanes * 4 u32
#define WS_NEEDED  ((size_t)(PWOFF_U32 + PWM_U32) * 4)

__global__ __launch_bounds__(256)
void pack_weights(const float* __restrict__ wmain,
                  const float* __restrict__ woff,
                  unsigned* __restrict__ pw)
{
    int idx = blockIdx.x * 256 + threadIdx.x;
    if (idx < PWOFF_U32) {
        int j2   = idx & 3;
        int lane = (idx >> 2) & 63;
        int rest = idx >> 8;              // t*5 + kt
        int kt   = rest % 5;
        int t    = rest / 5;
        int comp = t / 36, r36 = t - comp * 36;
        int jw   = r36 / 9, ntg = r36 - jw * 9;
        int ochb = comp * 576 + jw * 144 + ntg * 16;
        int g    = ochb / 432;
        int ktf  = (9 * g) >> 1;
        int och  = ochb + (lane & 15);
        int ck   = (ktf + kt) * 32 + (lane >> 4) * 8 + j2 * 2 - g * 144;
        float v0 = 0.f, v1 = 0.f;
        if ((unsigned)ck < 144u)       v0 = woff[(size_t)och * 144 + ck];
        if ((unsigned)(ck + 1) < 144u) v1 = woff[(size_t)och * 144 + ck + 1];
        pw[idx] = (unsigned)bf16rne(v0) | ((unsigned)bf16rne(v1) << 16);
    } else if (idx < PWOFF_U32 + PWM_U32) {
        int m    = idx - PWOFF_U32;
        int j2   = m & 3;
        int lane = (m >> 2) & 63;
        int rest = m >> 8;                // jw*5 + pair
        int jw   = rest / 5, pair = rest - jw * 5;
        int och  = jw * 16 + (lane & 15);
        int w0   = pair * 32 + (lane >> 4) * 8 + j2 * 2;
        float v0 = (w0 < 144)     ? wmain[(size_t)och * 144 + w0]     : 0.f;
        float v1 = (w0 + 1 < 144) ? wmain[(size_t)och * 144 + w0 + 1] : 0.f;
        pw[idx] = (unsigned)bf16rne(v0) | ((unsigned)bf16rne(v1) << 16);
    }
}

__global__ __launch_bounds__(256, 2)
void deform_v4(const float* __restrict__ inps,
               const float* __restrict__ bmain,
               const float* __restrict__ boff,
               const unsigned short* __restrict__ pwoff,
               const unsigned short* __restrict__ pwm,
               float* __restrict__ out)
{
    unsigned short* IMC   = (unsigned short*)(smem + IMC4_OFF);
    unsigned short* PATCH = (unsigned short*)(smem + PATCH4_OFF);
    unsigned short* SX    = (unsigned short*)(smem + SX4_OFF);
    unsigned short* LGX   = (unsigned short*)(smem + LGX4_OFF);
    float*          OTB   = (float*)(smem + OTB4_OFF);

    const int tid  = threadIdx.x;
    const int lane = tid & 63;
    const int jw   = __builtin_amdgcn_readfirstlane(tid >> 6);
    const int slot = lane & 15;
    const int q    = lane >> 4;

    const int b    = blockIdx.x >> 7;
    const int tile = blockIdx.x & 127;
    const int ty0  = (tile >> 3) << 2;     // 16 y-tiles of 4
    const int tx0  = (tile & 7) << 3;      // 8 x-tiles of 8

    const float* inb = inps + (size_t)b * 262144;

    // ---- phase 1: PATCH bf16 [64 ch][12 y][16 x] halo 4, zero OOB ----
    for (int e = tid; e < 12288; e += 256) {
        int c = e / 192, rem = e - c * 192;
        int y = rem >> 4, x = rem & 15;
        int gy = ty0 + y - 4, gx = tx0 + x - 4;
        float v = 0.f;
        if ((unsigned)gy < 64u && (unsigned)gx < 64u)
            v = inb[(c * 64 + gy) * 64 + gx];
        PATCH[c * 198 + rem] = bf16rne(v);
    }
    __syncthreads();

    // ---- phase 2: im2col IMC[px][kk], kk = c*9 + ky*3 + kx ----
    {
        const int px  = tid >> 3;          // 0..31
        const int sub = tid & 7;
        const int pyr = px >> 3, pxx = px & 7;
        unsigned* dst = (unsigned*)(IMC + px * 584);
        #pragma unroll 4
        for (int i = 0; i < 36; ++i) {
            int kk = i * 16 + sub * 2;
            int c0 = kk / 9,        r0 = kk - c0 * 9;
            int c1 = (kk + 1) / 9,  r1 = (kk + 1) - c1 * 9;
            unsigned short a  = PATCH[c0 * 198 + (pyr + r0 / 3 + 3) * 16 + pxx + r0 % 3 + 3];
            unsigned short bb = PATCH[c1 * 198 + (pyr + r1 / 3 + 3) * 16 + pxx + r1 % 3 + 3];
            dst[(unsigned)kk >> 1] = (unsigned)a | ((unsigned)bb << 16);
        }
    }
    __syncthreads();

    f32x4 aco[2] = {{0.f,0.f,0.f,0.f},{0.f,0.f,0.f,0.f}};

    auto pair_mfma = [&](int pair) {
        const short8 bfr = ((const short8*)pwm)[(jw * 5 + pair) * 64 + lane];
        #pragma unroll
        for (int mt = 0; mt < 2; ++mt) {
            const short8 a8 = *(const short8*)(SX + jw * 1280 + (mt * 16 + slot) * 40 + q * 8);
            aco[mt] = __builtin_amdgcn_mfma_f32_16x16x32_bf16(a8, bfr, aco[mt], 0, 0, 0);
        }
    };

    // ---- phase 3: ntg loop ----
    for (int ntg = 0; ntg < 9; ++ntg) {
        f32x4 aD[2] = {{0.f,0.f,0.f,0.f},{0.f,0.f,0.f,0.f}};
        f32x4 aX[2] = {{0.f,0.f,0.f,0.f},{0.f,0.f,0.f,0.f}};
        f32x4 aM[2] = {{0.f,0.f,0.f,0.f},{0.f,0.f,0.f,0.f}};

        auto gemm3 = [&](f32x4* acc, int comp) {
            const int ochb = comp * 576 + jw * 144 + ntg * 16;
            const int g    = ochb / 432;
            const int ktf  = (9 * g) >> 1;
            const int t    = comp * 36 + jw * 9 + ntg;
            const short8* wp  = (const short8*)pwoff + t * 320 + lane;   // + kt*64
            const short8* ap0 = (const short8*)(smem + IMC4_OFF);
            #pragma unroll
            for (int kt = 0; kt < 5; ++kt) {
                const short8 bfr = wp[kt * 64];
                const int ktg = ktf + kt;
                #pragma unroll
                for (int mt = 0; mt < 2; ++mt) {
                    const short8 af = ap0[(mt * 16 + slot) * 73 + ktg * 4 + q];
                    acc[mt] = __builtin_amdgcn_mfma_f32_16x16x32_bf16(af, bfr, acc[mt], 0, 0, 0);
                }
            }
            const float bo = boff[ochb + slot];
            #pragma unroll
            for (int mt = 0; mt < 2; ++mt) {
                acc[mt][0] += bo; acc[mt][1] += bo; acc[mt][2] += bo; acc[mt][3] += bo;
            }
        };
        gemm3(aD, 0); gemm3(aX, 1); gemm3(aM, 2);

        // logits -> LGX[px][slot][j] (cross-wave)
        #pragma unroll
        for (int mt = 0; mt < 2; ++mt)
        #pragma unroll
        for (int r = 0; r < 4; ++r) {
            int pxr = mt * 16 + q * 4 + r;
            LGX[pxr * 68 + slot * 4 + jw] = bf16rne(aM[mt][r]);
        }
        __syncthreads();

        // sampling (LDS patch fast path; global fallback for big offsets)
        const int rr  = ntg * 16 + slot;
        const int cg  = rr / 9;
        const int kk9 = rr - cg * 9;
        const int kyk = kk9 / 3, kxk = kk9 - kyk * 3;
        const int c   = jw * 16 + cg;
        const float* inc = inb + c * 4096;
        const int pbase = c * 198;
        const int par = ntg & 1;

        #pragma unroll
        for (int mt = 0; mt < 2; ++mt)
        #pragma unroll
        for (int r = 0; r < 4; ++r) {
            const int pxr = mt * 16 + q * 4 + r;
            const int pyr = pxr >> 3, pxx = pxr & 7;
            const float own = aM[mt][r];

            const uint2 lg = *(const uint2*)(LGX + pxr * 68 + slot * 4);
            float s4 = __expf(bf16dec((unsigned short)(lg.x & 0xFFFF)) - own)
                     + __expf(bf16dec((unsigned short)(lg.x >> 16))    - own)
                     + __expf(bf16dec((unsigned short)(lg.y & 0xFFFF)) - own)
                     + __expf(bf16dec((unsigned short)(lg.y >> 16))    - own);
            const float msk = 1.0f / s4;

            float pyf = (float)(ty0 + pyr + kyk - 1) + aD[mt][r];
            float pxf = (float)(tx0 + pxx + kxk - 1) + aX[mt][r];
            float y0f = floorf(pyf), x0f = floorf(pxf);
            float wy = pyf - y0f, wx = pxf - x0f;
            int iy0 = (int)y0f, ix0 = (int)x0f;
            float w00 = (1.f - wy) * (1.f - wx), w01 = (1.f - wy) * wx;
            float w10 = wy * (1.f - wx),         w11 = wy * wx;

            int ly0 = iy0 - ty0 + 4;
            int lx0 = ix0 - tx0 + 4;
            float v;
            if ((unsigned)ly0 < 11u && (unsigned)lx0 < 15u) {
                const int a = pbase + ly0 * 16 + lx0;
                v = w00 * bf16dec(PATCH[a])      + w01 * bf16dec(PATCH[a + 1])
                  + w10 * bf16dec(PATCH[a + 16]) + w11 * bf16dec(PATCH[a + 17]);
            } else {
                v = 0.f;
                if ((unsigned)iy0 < 64u) {
                    if ((unsigned)ix0 < 64u)       v += w00 * inc[iy0 * 64 + ix0];
                    if ((unsigned)(ix0 + 1) < 64u) v += w01 * inc[iy0 * 64 + ix0 + 1];
                }
                if ((unsigned)(iy0 + 1) < 64u) {
                    if ((unsigned)ix0 < 64u)       v += w10 * inc[(iy0 + 1) * 64 + ix0];
                    if ((unsigned)(ix0 + 1) < 64u) v += w11 * inc[(iy0 + 1) * 64 + ix0 + 1];
                }
            }
            SX[jw * 1280 + pxr * 40 + par * 16 + slot] = bf16rne(v * msk);
        }

        // main-conv partial GEMM every completed pair (same-wave SX -> no barrier)
        if (ntg & 1)  { asm volatile("" ::: "memory"); pair_mfma(ntg >> 1); }
        if (ntg == 8) { asm volatile("" ::: "memory"); pair_mfma(4); }
        __syncthreads();
    }

    // ---- epilogue: transpose via OTB (aliases PATCH), coalesced store ----
    {
        const int o = jw * 16 + slot;
        const float bo = bmain[o];
        #pragma unroll
        for (int mt = 0; mt < 2; ++mt)
        #pragma unroll
        for (int r = 0; r < 4; ++r)
            OTB[o * 33 + mt * 16 + q * 4 + r] = aco[mt][r] + bo;
    }
    __syncthreads();
    #pragma unroll
    for (int i = 0; i < 8; ++i) {
        int f  = i * 256 + tid;
        int oo = f >> 5, pp = f & 31;
        out[(size_t)(b * 64 + oo) * 4096 + (ty0 + (pp >> 3)) * 64 + (tx0 + (pp & 7))] =
            OTB[oo * 33 + pp];
    }
}

// ======================= v2 fallback (proven, 263 us) =======================
#define V2IMC_OFF   0
#define V2S_OFF     37376
#define V2LGX_OFF   74752
#define V2LDS_BYTES 78848

__global__ __launch_bounds__(256, 2)
void deform_v2(const float* __restrict__ inps,
               const float* __restrict__ wmain,
               const float* __restrict__ bmain,
               const float* __restrict__ woff,
               const float* __restrict__ boff,
               float* __restrict__ out)
{
    unsigned short* IMC  = (unsigned short*)(smem + V2IMC_OFF);
    unsigned short* SBUF = (unsigned short*)(smem + V2S_OFF);
    unsigned short* LGX  = (unsigned short*)(smem + V2LGX_OFF);
    float* PATCH = (float*)(smem + V2S_OFF);
    float* OTB   = (float*)(smem + V2IMC_OFF);

    const int tid  = threadIdx.x;
    const int lane = tid & 63;
    const int jw   = __builtin_amdgcn_readfirstlane(tid >> 6);
    const int slot = lane & 15;
    const int q    = lane >> 4;

    const int b    = blockIdx.x >> 7;
    const int tile = blockIdx.x & 127;
    const int ty0  = (tile >> 3) << 2;
    const int tx0  = (tile & 7) << 3;

    const float* inb = inps + (size_t)b * 262144;

    for (int e = tid; e < 64 * 60; e += 256) {
        int ch = e / 60, rem = e - ch * 60;
        int iy = rem / 10, ix = rem - iy * 10;
        int gy = ty0 + iy - 1, gx = tx0 + ix - 1;
        float v = 0.f;
        if ((unsigned)gy < 64u && (unsigned)gx < 64u)
            v = inb[(ch * 64 + gy) * 64 + gx];
        PATCH[ch * 61 + rem] = v;
    }
    __syncthreads();
    {
        const int px  = tid >> 3;
        const int sub = tid & 7;
        const int pyr = px >> 3, pxx = px & 7;
        unsigned short* dst = IMC + px * 584;
        for (int i = 0; i < 36; ++i) {
            int kk = sub * 72 + 2 * i;
            float v0, v1;
            { int c = kk / 9, r9 = kk - c * 9, ky = r9 / 3, kx = r9 - ky * 3;
              v0 = PATCH[c * 61 + (pyr + ky) * 10 + (pxx + kx)]; }
            { int k1 = kk + 1; int c = k1 / 9, r9 = k1 - c * 9, ky = r9 / 3, kx = r9 - ky * 3;
              v1 = PATCH[c * 61 + (pyr + ky) * 10 + (pxx + kx)]; }
            *(unsigned*)(dst + kk) = cvtpk2(v0, v1);
        }
    }
    __syncthreads();

    for (int ntg = 0; ntg < 9; ++ntg) {
        f32x4 aD[2] = {{0.f,0.f,0.f,0.f},{0.f,0.f,0.f,0.f}};
        f32x4 aX[2] = {{0.f,0.f,0.f,0.f},{0.f,0.f,0.f,0.f}};
        f32x4 aM[2] = {{0.f,0.f,0.f,0.f},{0.f,0.f,0.f,0.f}};

        auto gemm3 = [&](f32x4* acc, int comp) {
            const int ochb = comp * 576 + jw * 144 + ntg * 16;
            const int g    = ochb / 432;
            const int ktf  = (9 * g) >> 1;
            const int ch0  = g * 18;
            const int och  = ochb + slot;
            #pragma unroll
            for (int kt = 0; kt < 5; ++kt) {
                const int ktg   = ktf + kt;
                const int chunk = ktg * 4 + q;
                short8 bfr;
                if ((unsigned)(chunk - ch0) < 18u) {
                    const float4* wp = (const float4*)(woff + (size_t)och * 144 + (chunk - ch0) * 8);
                    float4 w0 = wp[0], w1 = wp[1];
                    union { unsigned u[4]; short8 s; } cv;
                    cv.u[0] = cvtpk2(w0.x, w0.y); cv.u[1] = cvtpk2(w0.z, w0.w);
                    cv.u[2] = cvtpk2(w1.x, w1.y); cv.u[3] = cvtpk2(w1.z, w1.w);
                    bfr = cv.s;
                } else {
                    bfr = short8{0,0,0,0,0,0,0,0};
                }
                #pragma unroll
                for (int mt = 0; mt < 2; ++mt) {
                    const short8* ap = (const short8*)(smem + V2IMC_OFF +
                                        (mt * 16 + slot) * 1168 + ktg * 64 + q * 16);
                    acc[mt] = __builtin_amdgcn_mfma_f32_16x16x32_bf16(*ap, bfr, acc[mt], 0, 0, 0);
                }
            }
            const float bo = boff[ochb + slot];
            #pragma unroll
            for (int mt = 0; mt < 2; ++mt) {
                acc[mt][0] += bo; acc[mt][1] += bo; acc[mt][2] += bo; acc[mt][3] += bo;
            }
        };
        gemm3(aD, 0); gemm3(aX, 1); gemm3(aM, 2);

        #pragma unroll
        for (int mt = 0; mt < 2; ++mt)
        #pragma unroll
        for (int r = 0; r < 4; ++r) {
            int pxr = mt * 16 + q * 4 + r;
            LGX[(jw * 32 + pxr) * 16 + slot] = bf16rne(aM[mt][r]);
        }
        __syncthreads();

        const int rr  = ntg * 16 + slot;
        const int cg  = rr / 9;
        const int kk9 = rr - cg * 9;
        const int kyk = kk9 / 3, kxk = kk9 - kyk * 3;
        const float* inc = inb + (jw * 16 + cg) * 4096;

        #pragma unroll
        for (int mt = 0; mt < 2; ++mt)
        #pragma unroll
        for (int r = 0; r < 4; ++r) {
            const int pxr = mt * 16 + q * 4 + r;
            const int pyr = pxr >> 3, pxx = pxr & 7;
            float own = aM[mt][r];
            float l0 = (jw == 0) ? own : bf16dec(LGX[(0 * 32 + pxr) * 16 + slot]);
            float l1 = (jw == 1) ? own : bf16dec(LGX[(1 * 32 + pxr) * 16 + slot]);
            float l2 = (jw == 2) ? own : bf16dec(LGX[(2 * 32 + pxr) * 16 + slot]);
            float l3 = (jw == 3) ? own : bf16dec(LGX[(3 * 32 + pxr) * 16 + slot]);
            float m4 = fmaxf(fmaxf(l0, l1), fmaxf(l2, l3));
            float s4 = __expf(l0 - m4) + __expf(l1 - m4) + __expf(l2 - m4) + __expf(l3 - m4);
            float msk = __expf(own - m4) / s4;

            float pyf = (float)(ty0 + pyr + kyk - 1) + aD[mt][r];
            float pxf = (float)(tx0 + pxx + kxk - 1) + aX[mt][r];
            float y0f = floorf(pyf), x0f = floorf(pxf);
            float wy = pyf - y0f, wx = pxf - x0f;
            int iy0 = (int)y0f, ix0 = (int)x0f;
            float w00 = (1.f - wy) * (1.f - wx), w01 = (1.f - wy) * wx;
            float w10 = wy * (1.f - wx),         w11 = wy * wx;
            float v = 0.f;
            if ((unsigned)iy0 < 64u) {
                if ((unsigned)ix0 < 64u)       v += w00 * inc[iy0 * 64 + ix0];
                if ((unsigned)(ix0 + 1) < 64u) v += w01 * inc[iy0 * 64 + ix0 + 1];
            }
            if ((unsigned)(iy0 + 1) < 64u) {
                if ((unsigned)ix0 < 64u)       v += w10 * inc[(iy0 + 1) * 64 + ix0];
                if ((unsigned)(ix0 + 1) < 64u) v += w11 * inc[(iy0 + 1) * 64 + ix0 + 1];
            }
            SBUF[pxr * 584 + jw * 144 + rr] = bf16rne(v * msk);
        }
        __syncthreads();
    }

    {
        f32x4 aco2[2] = {{0.f,0.f,0.f,0.f},{0.f,0.f,0.f,0.f}};
        const int ktf = (9 * jw) >> 1;
        const int ch0 = jw * 18;
        const int o   = jw * 16 + slot;
        #pragma unroll
        for (int kt = 0; kt < 5; ++kt) {
            const int ktg   = ktf + kt;
            const int chunk = ktg * 4 + q;
            short8 bfr;
            if ((unsigned)(chunk - ch0) < 18u) {
                const float4* wp = (const float4*)(wmain + (size_t)o * 144 + (chunk - ch0) * 8);
                float4 w0 = wp[0], w1 = wp[1];
                union { unsigned u[4]; short8 s; } cv;
                cv.u[0] = cvtpk2(w0.x, w0.y); cv.u[1] = cvtpk2(w0.z, w0.w);
                cv.u[2] = cvtpk2(w1.x, w1.y); cv.u[3] = cvtpk2(w1.z, w1.w);
                bfr = cv.s;
            } else {
                bfr = short8{0,0,0,0,0,0,0,0};
            }
            #pragma unroll
            for (int mt = 0; mt < 2; ++mt) {
                const short8* ap = (const short8*)(smem + V2S_OFF +
                                    (mt * 16 + slot) * 1168 + ktg * 64 + q * 16);
                aco2[mt] = __builtin_amdgcn_mfma_f32_16x16x32_bf16(*ap, bfr, aco2[mt], 0, 0, 0);
            }
        }
        const float bo = bmain[o];
        __syncthreads();
        #pragma unroll
        for (int mt = 0; mt < 2; ++mt)
        #pragma unroll
        for (int r = 0; r < 4; ++r)
            OTB[o * 33 + mt * 16 + q * 4 + r] = aco2[mt][r] + bo;
    }
    __syncthreads();
    #pragma unroll
    for (int i = 0; i < 8; ++i) {
        int f  = i * 256 + tid;
        int oo = f >> 5, pp = f & 31;
        out[(size_t)(b * 64 + oo) * 4096 + (ty0 + (pp >> 3)) * 64 + (tx0 + (pp & 7))] =
            OTB[oo * 33 + pp];
    }
}

extern "C" void kernel_launch(void* const* d_in, const int* in_sizes, int n_in,
                              void* d_out, int out_size, void* d_ws, size_t ws_size,
                              hipStream_t stream) {
    const float* inps   = (const float*)d_in[0];
    const float* weight = (const float*)d_in[1];
    const float* bias   = (const float*)d_in[2];
    const float* woff   = (const float*)d_in[3];
    const float* boff   = (const float*)d_in[4];
    float* outp = (float*)d_out;

    if (ws_size >= WS_NEEDED) {
        unsigned* pw = (unsigned*)d_ws;
        pack_weights<<<dim3(560), dim3(256), 0, stream>>>(weight, woff, pw);
        hipFuncSetAttribute((const void*)deform_v4,
                            hipFuncAttributeMaxDynamicSharedMemorySize, LDS_V4);
        deform_v4<<<dim3(1024), dim3(256), LDS_V4, stream>>>(
            inps, bias, boff,
            (const unsigned short*)pw,
            (const unsigned short*)(pw + PWOFF_U32), outp);
    } else {
        hipFuncSetAttribute((const void*)deform_v2,
                            hipFuncAttributeMaxDynamicSharedMemorySize, V2LDS_BYTES);
        deform_v2<<<dim3(1024), dim3(256), V2LDS_BYTES, stream>>>(
            inps, weight, bias, woff, boff, outp);
    }
}